// Round 1
// baseline (3192.785 us; speedup 1.0000x reference)
//
#include <hip/hip_runtime.h>

#define DD 64

static inline int ceil_div_l(long long a, int b) { return (int)((a + b - 1) / b); }

__global__ void k_deg_init(int* __restrict__ deg, int n) {
    int i = blockIdx.x * blockDim.x + threadIdx.x;
    if (i < n) deg[i] = 1;  // self loop
}

__global__ void k_deg_count(const int* __restrict__ edges, int* __restrict__ deg,
                            int E, int nu) {
    int e = blockIdx.x * blockDim.x + threadIdx.x;
    if (e < E) {
        atomicAdd(&deg[edges[e]], 1);            // src (user)
        atomicAdd(&deg[nu + edges[E + e]], 1);   // dst (item, offset)
    }
}

__global__ void k_dinv(int* __restrict__ buf, int n) {
    int i = blockIdx.x * blockDim.x + threadIdx.x;
    if (i < n) {
        float d = (float)buf[i];
        ((float*)buf)[i] = rsqrtf(d);
    }
}

// h = x (concat user_w, item_w); out(acc) = x
__global__ void k_init(const float* __restrict__ uw, const float* __restrict__ iw,
                       float* __restrict__ h, float* __restrict__ out,
                       int nElem, int nuD) {
    int idx = blockIdx.x * blockDim.x + threadIdx.x;
    if (idx < nElem) {
        float x = (idx < nuD) ? uw[idx] : iw[idx - nuD];
        h[idx] = x;
        out[idx] = x;
    }
}

// hn = dinv^2 * h   (self-loop contribution, also zero-initializes hn)
__global__ void k_selfinit(const float* __restrict__ dinv, const float* __restrict__ h,
                           float* __restrict__ hn, int nElem) {
    int idx = blockIdx.x * blockDim.x + threadIdx.x;
    if (idx < nElem) {
        float s = dinv[idx >> 6];
        hn[idx] = s * s * h[idx];
    }
}

// out += hsrc;  hn = dinv^2 * hsrc   (accumulate layer + init next layer's buffer)
__global__ void k_acc_selfinit(const float* __restrict__ dinv, const float* __restrict__ hsrc,
                               float* __restrict__ hn, float* __restrict__ out, int nElem) {
    int idx = blockIdx.x * blockDim.x + threadIdx.x;
    if (idx < nElem) {
        float v = hsrc[idx];
        out[idx] += v;
        float s = dinv[idx >> 6];
        hn[idx] = s * s * v;
    }
}

// per directed edge pair: hn[c] += dinv[r]*dinv[c]*h[r] (both directions)
__global__ void k_scatter(const int* __restrict__ edges, const float* __restrict__ dinv,
                          const float* __restrict__ h, float* __restrict__ hn,
                          int E, int nu) {
    int t = blockIdx.x * blockDim.x + threadIdx.x;
    int e = t >> 6;
    int d = t & 63;
    if (e >= E) return;
    int u = edges[e];
    int w = nu + edges[E + e];
    float norm = dinv[u] * dinv[w];
    float hu = h[u * DD + d];
    float hw = h[w * DD + d];
    unsafeAtomicAdd(&hn[w * DD + d], norm * hu);
    unsafeAtomicAdd(&hn[u * DD + d], norm * hw);
}

// out = mix((out + hlast) * 0.25)
__global__ void k_final(const float* __restrict__ hlast, const float* __restrict__ uw,
                        const float* __restrict__ aw, float* __restrict__ out,
                        int nElem, int nuD) {
    int idx = blockIdx.x * blockDim.x + threadIdx.x;
    if (idx < nElem) {
        float interest = (out[idx] + hlast[idx]) * 0.25f;
        if (idx < nuD) {
            float a0 = aw[0], a1 = aw[1];
            float e0 = expf(a0), e1 = expf(a1);
            float al0 = e0 / (e0 + e1);
            float al1 = 1.0f - al0;
            out[idx] = al0 * interest + al1 * uw[idx];
        } else {
            out[idx] = interest;
        }
    }
}

extern "C" void kernel_launch(void* const* d_in, const int* in_sizes, int n_in,
                              void* d_out, int out_size, void* d_ws, size_t ws_size,
                              hipStream_t stream) {
    const int* edges = (const int*)d_in[0];     // (2,E): src[0..E), dst[E..2E)
    const float* uw = (const float*)d_in[1];    // (nu, 64)
    const float* iw = (const float*)d_in[2];    // (ni, 64)
    const float* aw = (const float*)d_in[3];    // (2,)
    float* out = (float*)d_out;

    const int E = in_sizes[0] / 2;
    const int nu = in_sizes[1] / DD;
    const int ni = in_sizes[2] / DD;
    const int n = nu + ni;
    const int nElem = n * DD;
    const int nuD = nu * DD;

    char* ws = (char*)d_ws;
    int* deg = (int*)ws;                               // n ints -> reused as float dinv
    float* dinv = (float*)ws;
    size_t offA = (((size_t)n * 4) + 255) & ~(size_t)255;
    float* hA = (float*)(ws + offA);                   // n*64 f32
    size_t offB = offA + ((((size_t)nElem * 4) + 255) & ~(size_t)255);
    float* hB = (float*)(ws + offB);                   // n*64 f32

    const int B = 256;
    const int gN = ceil_div_l(n, B);
    const int gE = ceil_div_l(E, B);
    const int gEl = ceil_div_l(nElem, B);
    const int gS = ceil_div_l((long long)E * DD, B);

    // degrees -> dinv
    k_deg_init<<<gN, B, 0, stream>>>(deg, n);
    k_deg_count<<<gE, B, 0, stream>>>(edges, deg, E, nu);
    k_dinv<<<gN, B, 0, stream>>>(deg, n);

    // h0 = x, acc = x
    k_init<<<gEl, B, 0, stream>>>(uw, iw, hA, out, nElem, nuD);

    // layer 1: hA -> hB
    k_selfinit<<<gEl, B, 0, stream>>>(dinv, hA, hB, nElem);
    k_scatter<<<gS, B, 0, stream>>>(edges, dinv, hA, hB, E, nu);

    // acc += h1; layer 2: hB -> hA
    k_acc_selfinit<<<gEl, B, 0, stream>>>(dinv, hB, hA, out, nElem);
    k_scatter<<<gS, B, 0, stream>>>(edges, dinv, hB, hA, E, nu);

    // acc += h2; layer 3: hA -> hB
    k_acc_selfinit<<<gEl, B, 0, stream>>>(dinv, hA, hB, out, nElem);
    k_scatter<<<gS, B, 0, stream>>>(edges, dinv, hA, hB, E, nu);

    // acc += h3; interest = acc/4; user mix
    k_final<<<gEl, B, 0, stream>>>(hB, uw, aw, out, nElem, nuD);
}

// Round 2
// 2339.848 us; speedup vs baseline: 1.3645x; 1.3645x over previous
//
#include <hip/hip_runtime.h>

#define DD 64
#define SC_T 256
#define SC_E 4
#define SC_B 1024   // elements scanned per block

static inline int cdiv(long long a, int b) { return (int)((a + b - 1) / b); }

__global__ void k_zero(int* __restrict__ p, int n) {
    int i = blockIdx.x * blockDim.x + threadIdx.x;
    if (i < n) p[i] = 0;
}

// real degrees (no self loop; self handled analytically)
__global__ void k_deg_count(const int* __restrict__ edges, int* __restrict__ deg,
                            int E, int nu) {
    int e = blockIdx.x * blockDim.x + threadIdx.x;
    if (e < E) {
        atomicAdd(&deg[edges[e]], 1);
        atomicAdd(&deg[nu + edges[E + e]], 1);
    }
}

// per-block sums of deg
__global__ void k_scan1(const int* __restrict__ deg, int* __restrict__ bsum, int n) {
    __shared__ int lds[SC_T];
    int tid = threadIdx.x;
    int base = blockIdx.x * SC_B + tid * SC_E;
    int s = 0;
#pragma unroll
    for (int j = 0; j < SC_E; j++) { int i = base + j; if (i < n) s += deg[i]; }
    lds[tid] = s; __syncthreads();
    for (int off = SC_T / 2; off > 0; off >>= 1) {
        if (tid < off) lds[tid] += lds[tid + off];
        __syncthreads();
    }
    if (tid == 0) bsum[blockIdx.x] = lds[0];
}

// exclusive scan of block sums (nb <= 1024)
__global__ void k_scan2(int* __restrict__ bsum, int nb) {
    __shared__ int lds[1024];
    int tid = threadIdx.x;
    int v = (tid < nb) ? bsum[tid] : 0;
    lds[tid] = v; __syncthreads();
    for (int off = 1; off < 1024; off <<= 1) {
        int t = (tid >= off) ? lds[tid - off] : 0;
        __syncthreads();
        lds[tid] += t;
        __syncthreads();
    }
    if (tid < nb) bsum[tid] = lds[tid] - v;   // exclusive
}

// write ptr (exclusive prefix), cursor (=ptr, into deg in place), dinv = rsqrt(deg+1)
__global__ void k_scan3(int* __restrict__ deg, const int* __restrict__ bsum,
                        int* __restrict__ ptr, float* __restrict__ dinv, int n) {
    __shared__ int lds[SC_T];
    int tid = threadIdx.x;
    int base = blockIdx.x * SC_B + tid * SC_E;
    int v[SC_E]; int s = 0;
#pragma unroll
    for (int j = 0; j < SC_E; j++) { int i = base + j; v[j] = (i < n) ? deg[i] : 0; s += v[j]; }
    lds[tid] = s; __syncthreads();
    for (int off = 1; off < SC_T; off <<= 1) {
        int t = (tid >= off) ? lds[tid - off] : 0;
        __syncthreads();
        lds[tid] += t;
        __syncthreads();
    }
    int run = bsum[blockIdx.x] + lds[tid] - s;   // exclusive over all prior elems
#pragma unroll
    for (int j = 0; j < SC_E; j++) {
        int i = base + j;
        if (i < n) {
            ptr[i] = run;
            deg[i] = run;                          // becomes fill cursor
            dinv[i] = rsqrtf((float)(v[j] + 1));   // +1 self loop
            run += v[j];
        }
    }
}

__global__ void k_fill(const int* __restrict__ edges, int* __restrict__ cursor,
                       int* __restrict__ adj, int E, int nu) {
    int e = blockIdx.x * blockDim.x + threadIdx.x;
    if (e < E) {
        int u = edges[e];
        int w = nu + edges[E + e];
        int p1 = atomicAdd(&cursor[w], 1); adj[p1] = u;
        int p2 = atomicAdd(&cursor[u], 1); adj[p2] = w;
    }
}

__global__ void k_init(const float* __restrict__ uw, const float* __restrict__ iw,
                       float* __restrict__ h, int nElem, int nuD) {
    int i = blockIdx.x * blockDim.x + threadIdx.x;
    if (i < nElem) h[i] = (i < nuD) ? uw[i] : iw[i - nuD];
}

// wave-per-node gather: res[c,d] = dinv[c]*(dinv[c]*h[c,d] + sum_r dinv[r]*h[r,d])
// MODE 1: hn=res, out = h(c) + res          (acc = x + h1)
// MODE 2: hn=res, out += res                (acc += h2)
// MODE 3: epilogue: interest=(out+res)/4, user mix; h3 stays in registers
template <int MODE>
__global__ void k_gather(const int* __restrict__ ptr, const int* __restrict__ adj,
                         const float* __restrict__ dinv, const float* __restrict__ h,
                         float* __restrict__ hn, float* __restrict__ out,
                         const float* __restrict__ uw, const float* __restrict__ aw,
                         int n, int twoE, int nuD) {
    int t = blockIdx.x * blockDim.x + threadIdx.x;
    int c = t >> 6;
    int d = t & 63;
    if (c >= n) return;
    float dc = dinv[c];
    int s = ptr[c];
    int e = (c == n - 1) ? twoE : ptr[c + 1];
    float hc = h[c * DD + d];
    float acc = dc * hc;
    for (int k = s; k < e; k++) {
        int r = adj[k];
        acc += dinv[r] * h[r * DD + d];
    }
    float res = dc * acc;
    int idx = c * DD + d;
    if (MODE == 1) {
        hn[idx] = res;
        out[idx] = hc + res;
    } else if (MODE == 2) {
        hn[idx] = res;
        out[idx] += res;
    } else {
        float interest = (out[idx] + res) * 0.25f;
        if (idx < nuD) {
            float a0 = aw[0], a1 = aw[1];
            float m = fmaxf(a0, a1);
            float e0 = expf(a0 - m), e1 = expf(a1 - m);
            float al0 = e0 / (e0 + e1);
            out[idx] = al0 * interest + (1.0f - al0) * uw[idx];
        } else {
            out[idx] = interest;
        }
    }
}

extern "C" void kernel_launch(void* const* d_in, const int* in_sizes, int n_in,
                              void* d_out, int out_size, void* d_ws, size_t ws_size,
                              hipStream_t stream) {
    const int* edges = (const int*)d_in[0];   // (2,E)
    const float* uw = (const float*)d_in[1];  // (nu,64)
    const float* iw = (const float*)d_in[2];  // (ni,64)
    const float* aw = (const float*)d_in[3];  // (2,)
    float* out = (float*)d_out;

    const int E = in_sizes[0] / 2;
    const int nu = in_sizes[1] / DD;
    const int ni = in_sizes[2] / DD;
    const int n = nu + ni;
    const int nElem = n * DD;
    const int nuD = nu * DD;
    const int twoE = 2 * E;

    // workspace layout
    char* ws = (char*)d_ws;
    size_t off = 0;
    auto alloc = [&](size_t bytes) { size_t r = off; off = (off + bytes + 255) & ~(size_t)255; return r; };
    int* deg   = (int*)(ws + alloc((size_t)n * 4));        // -> cursor after scan3
    int* bsum  = (int*)(ws + alloc((size_t)cdiv(n, SC_B) * 4));
    int* ptr   = (int*)(ws + alloc((size_t)n * 4));
    float* dinv= (float*)(ws + alloc((size_t)n * 4));
    int* adj   = (int*)(ws + alloc((size_t)twoE * 4));
    float* hA  = (float*)(ws + alloc((size_t)nElem * 4));
    float* hB  = (float*)(ws + alloc((size_t)nElem * 4));

    const int B = 256;
    const int gN  = cdiv(n, B);
    const int gE  = cdiv(E, B);
    const int gEl = cdiv(nElem, B);
    const int nb  = cdiv(n, SC_B);
    const int gW  = cdiv((long long)n * 64, B);

    // CSR build
    k_zero<<<gN, B, 0, stream>>>(deg, n);
    k_deg_count<<<gE, B, 0, stream>>>(edges, deg, E, nu);
    k_scan1<<<nb, SC_T, 0, stream>>>(deg, bsum, n);
    k_scan2<<<1, 1024, 0, stream>>>(bsum, nb);
    k_scan3<<<nb, SC_T, 0, stream>>>(deg, bsum, ptr, dinv, n);
    k_fill<<<gE, B, 0, stream>>>(edges, deg /*cursor*/, adj, E, nu);

    // h0 = x
    k_init<<<gEl, B, 0, stream>>>(uw, iw, hA, nElem, nuD);

    // layer 1: hA->hB, out = x + h1
    k_gather<1><<<gW, B, 0, stream>>>(ptr, adj, dinv, hA, hB, out, uw, aw, n, twoE, nuD);
    // layer 2: hB->hA, out += h2
    k_gather<2><<<gW, B, 0, stream>>>(ptr, adj, dinv, hB, hA, out, uw, aw, n, twoE, nuD);
    // layer 3: hA->(reg), fused epilogue
    k_gather<3><<<gW, B, 0, stream>>>(ptr, adj, dinv, hA, hB, out, uw, aw, n, twoE, nuD);
}

// Round 3
// 1650.547 us; speedup vs baseline: 1.9344x; 1.4176x over previous
//
#include <hip/hip_runtime.h>

#define DD 64
#define SC_T 256
#define SC_E 4
#define SC_B 1024   // elements scanned per block

static inline int cdiv(long long a, int b) { return (int)((a + b - 1) / b); }

__global__ void k_zero(int* __restrict__ p, int n) {
    int i = blockIdx.x * blockDim.x + threadIdx.x;
    if (i < n) p[i] = 0;
}

// real degrees (no self loop; self handled analytically)
__global__ void k_deg_count(const int* __restrict__ edges, int* __restrict__ deg,
                            int E, int nu) {
    int e = blockIdx.x * blockDim.x + threadIdx.x;
    if (e < E) {
        atomicAdd(&deg[edges[e]], 1);
        atomicAdd(&deg[nu + edges[E + e]], 1);
    }
}

// per-block sums of deg
__global__ void k_scan1(const int* __restrict__ deg, int* __restrict__ bsum, int n) {
    __shared__ int lds[SC_T];
    int tid = threadIdx.x;
    int base = blockIdx.x * SC_B + tid * SC_E;
    int s = 0;
#pragma unroll
    for (int j = 0; j < SC_E; j++) { int i = base + j; if (i < n) s += deg[i]; }
    lds[tid] = s; __syncthreads();
    for (int off = SC_T / 2; off > 0; off >>= 1) {
        if (tid < off) lds[tid] += lds[tid + off];
        __syncthreads();
    }
    if (tid == 0) bsum[blockIdx.x] = lds[0];
}

// exclusive scan of block sums (nb <= 1024)
__global__ void k_scan2(int* __restrict__ bsum, int nb) {
    __shared__ int lds[1024];
    int tid = threadIdx.x;
    int v = (tid < nb) ? bsum[tid] : 0;
    lds[tid] = v; __syncthreads();
    for (int off = 1; off < 1024; off <<= 1) {
        int t = (tid >= off) ? lds[tid - off] : 0;
        __syncthreads();
        lds[tid] += t;
        __syncthreads();
    }
    if (tid < nb) bsum[tid] = lds[tid] - v;   // exclusive
}

// write ptr (exclusive prefix), cursor (into deg in place), dinv = rsqrt(deg+1)
__global__ void k_scan3(int* __restrict__ deg, const int* __restrict__ bsum,
                        int* __restrict__ ptr, float* __restrict__ dinv, int n) {
    __shared__ int lds[SC_T];
    int tid = threadIdx.x;
    int base = blockIdx.x * SC_B + tid * SC_E;
    int v[SC_E]; int s = 0;
#pragma unroll
    for (int j = 0; j < SC_E; j++) { int i = base + j; v[j] = (i < n) ? deg[i] : 0; s += v[j]; }
    lds[tid] = s; __syncthreads();
    for (int off = 1; off < SC_T; off <<= 1) {
        int t = (tid >= off) ? lds[tid - off] : 0;
        __syncthreads();
        lds[tid] += t;
        __syncthreads();
    }
    int run = bsum[blockIdx.x] + lds[tid] - s;   // exclusive over all prior elems
#pragma unroll
    for (int j = 0; j < SC_E; j++) {
        int i = base + j;
        if (i < n) {
            ptr[i] = run;
            deg[i] = run;                          // becomes fill cursor
            dinv[i] = rsqrtf((float)(v[j] + 1));   // +1 self loop
            run += v[j];
        }
    }
}

__global__ void k_fill(const int* __restrict__ edges, int* __restrict__ cursor,
                       int* __restrict__ adj, int E, int nu) {
    int e = blockIdx.x * blockDim.x + threadIdx.x;
    if (e < E) {
        int u = edges[e];
        int w = nu + edges[E + e];
        int p1 = atomicAdd(&cursor[w], 1); adj[p1] = u;
        int p2 = atomicAdd(&cursor[u], 1); adj[p2] = w;
    }
}

// g0 = dinv .* x   (pre-scaled feature)
__global__ void k_init(const float* __restrict__ uw, const float* __restrict__ iw,
                       const float* __restrict__ dinv, float* __restrict__ g,
                       int nElem, int nuD) {
    int i = blockIdx.x * blockDim.x + threadIdx.x;
    if (i < nElem) {
        float x = (i < nuD) ? uw[i] : iw[i - nuD];
        g[i] = dinv[i >> 6] * x;
    }
}

// wave-per-node gather in g-space:
//   res[c,d] = h_{l+1}[c,d] = dc * (g[c,d] + sum_{r in N(c)} g[r,d])
//   g_next   = dc * res
// MODE 1: gn = dc*res, out = x + res   (x = g[c]/dc)
// MODE 2: gn = dc*res, out += res
// MODE 3: fused epilogue, no gn write
template <int MODE>
__global__ void k_gather(const int* __restrict__ ptr, const int* __restrict__ adj,
                         const float* __restrict__ dinv, const float* __restrict__ g,
                         float* __restrict__ gn, float* __restrict__ out,
                         const float* __restrict__ uw, const float* __restrict__ aw,
                         int n, int twoE, int nuD) {
    int t = blockIdx.x * blockDim.x + threadIdx.x;
    int c = t >> 6;
    int d = t & 63;
    if (c >= n) return;
    float dc = dinv[c];
    int s = ptr[c];
    int e = (c == n - 1) ? twoE : ptr[c + 1];
    float gc = g[(size_t)c * DD + d];
    float acc = gc;
    for (int base = s; base < e; base += 64) {
        int cnt = e - base; if (cnt > 64) cnt = 64;
        int myr = (d < cnt) ? adj[base + d] : 0;
        int k = 0;
        for (; k + 4 <= cnt; k += 4) {
            int r0 = __shfl(myr, k, 64);
            int r1 = __shfl(myr, k + 1, 64);
            int r2 = __shfl(myr, k + 2, 64);
            int r3 = __shfl(myr, k + 3, 64);
            float v0 = g[(size_t)r0 * DD + d];
            float v1 = g[(size_t)r1 * DD + d];
            float v2 = g[(size_t)r2 * DD + d];
            float v3 = g[(size_t)r3 * DD + d];
            acc += v0; acc += v1; acc += v2; acc += v3;
        }
        for (; k < cnt; k++) {
            int r = __shfl(myr, k, 64);
            acc += g[(size_t)r * DD + d];
        }
    }
    float res = dc * acc;
    size_t idx = (size_t)c * DD + d;
    if (MODE == 1) {
        gn[idx] = dc * res;
        out[idx] = gc / dc + res;      // x + h1
    } else if (MODE == 2) {
        gn[idx] = dc * res;
        out[idx] += res;
    } else {
        float interest = (out[idx] + res) * 0.25f;
        if (idx < (size_t)nuD) {
            float a0 = aw[0], a1 = aw[1];
            float m = fmaxf(a0, a1);
            float e0 = expf(a0 - m), e1 = expf(a1 - m);
            float al0 = e0 / (e0 + e1);
            out[idx] = al0 * interest + (1.0f - al0) * uw[idx];
        } else {
            out[idx] = interest;
        }
    }
}

extern "C" void kernel_launch(void* const* d_in, const int* in_sizes, int n_in,
                              void* d_out, int out_size, void* d_ws, size_t ws_size,
                              hipStream_t stream) {
    const int* edges = (const int*)d_in[0];   // (2,E)
    const float* uw = (const float*)d_in[1];  // (nu,64)
    const float* iw = (const float*)d_in[2];  // (ni,64)
    const float* aw = (const float*)d_in[3];  // (2,)
    float* out = (float*)d_out;

    const int E = in_sizes[0] / 2;
    const int nu = in_sizes[1] / DD;
    const int ni = in_sizes[2] / DD;
    const int n = nu + ni;
    const int nElem = n * DD;
    const int nuD = nu * DD;
    const int twoE = 2 * E;

    // workspace layout
    char* ws = (char*)d_ws;
    size_t off = 0;
    auto alloc = [&](size_t bytes) { size_t r = off; off = (off + bytes + 255) & ~(size_t)255; return r; };
    int* deg   = (int*)(ws + alloc((size_t)n * 4));        // -> cursor after scan3
    int* bsum  = (int*)(ws + alloc((size_t)cdiv(n, SC_B) * 4));
    int* ptr   = (int*)(ws + alloc((size_t)n * 4));
    float* dinv= (float*)(ws + alloc((size_t)n * 4));
    int* adj   = (int*)(ws + alloc((size_t)twoE * 4));
    float* gA  = (float*)(ws + alloc((size_t)nElem * 4));
    float* gB  = (float*)(ws + alloc((size_t)nElem * 4));

    const int B = 256;
    const int gN  = cdiv(n, B);
    const int gE  = cdiv(E, B);
    const int gEl = cdiv(nElem, B);
    const int nb  = cdiv(n, SC_B);
    const int gW  = cdiv((long long)n * 64, B);

    // CSR build
    k_zero<<<gN, B, 0, stream>>>(deg, n);
    k_deg_count<<<gE, B, 0, stream>>>(edges, deg, E, nu);
    k_scan1<<<nb, SC_T, 0, stream>>>(deg, bsum, n);
    k_scan2<<<1, 1024, 0, stream>>>(bsum, nb);
    k_scan3<<<nb, SC_T, 0, stream>>>(deg, bsum, ptr, dinv, n);
    k_fill<<<gE, B, 0, stream>>>(edges, deg /*cursor*/, adj, E, nu);

    // g0 = dinv .* x
    k_init<<<gEl, B, 0, stream>>>(uw, iw, dinv, gA, nElem, nuD);

    // layer 1: gA->gB, out = x + h1
    k_gather<1><<<gW, B, 0, stream>>>(ptr, adj, dinv, gA, gB, out, uw, aw, n, twoE, nuD);
    // layer 2: gB->gA, out += h2
    k_gather<2><<<gW, B, 0, stream>>>(ptr, adj, dinv, gB, gA, out, uw, aw, n, twoE, nuD);
    // layer 3: gA->(reg), fused epilogue
    k_gather<3><<<gW, B, 0, stream>>>(ptr, adj, dinv, gA, gB, out, uw, aw, n, twoE, nuD);
}

// Round 5
// 1255.613 us; speedup vs baseline: 2.5428x; 1.3145x over previous
//
#include <hip/hip_runtime.h>

#define DD 64
#define SC_T 256
#define SC_E 4
#define SC_B 1024   // elements scanned per block

typedef float f32x4 __attribute__((ext_vector_type(4)));

static inline int cdiv(long long a, int b) { return (int)((a + b - 1) / b); }

__global__ void k_zero(int* __restrict__ p, int n) {
    int i = blockIdx.x * blockDim.x + threadIdx.x;
    if (i < n) p[i] = 0;
}

__global__ void k_deg_count(const int* __restrict__ edges, int* __restrict__ deg,
                            int E, int nu) {
    int e = blockIdx.x * blockDim.x + threadIdx.x;
    if (e < E) {
        atomicAdd(&deg[edges[e]], 1);
        atomicAdd(&deg[nu + edges[E + e]], 1);
    }
}

__global__ void k_scan1(const int* __restrict__ deg, int* __restrict__ bsum, int n) {
    __shared__ int lds[SC_T];
    int tid = threadIdx.x;
    int base = blockIdx.x * SC_B + tid * SC_E;
    int s = 0;
#pragma unroll
    for (int j = 0; j < SC_E; j++) { int i = base + j; if (i < n) s += deg[i]; }
    lds[tid] = s; __syncthreads();
    for (int off = SC_T / 2; off > 0; off >>= 1) {
        if (tid < off) lds[tid] += lds[tid + off];
        __syncthreads();
    }
    if (tid == 0) bsum[blockIdx.x] = lds[0];
}

__global__ void k_scan2(int* __restrict__ bsum, int nb) {
    __shared__ int lds[1024];
    int tid = threadIdx.x;
    int v = (tid < nb) ? bsum[tid] : 0;
    lds[tid] = v; __syncthreads();
    for (int off = 1; off < 1024; off <<= 1) {
        int t = (tid >= off) ? lds[tid - off] : 0;
        __syncthreads();
        lds[tid] += t;
        __syncthreads();
    }
    if (tid < nb) bsum[tid] = lds[tid] - v;   // exclusive
}

__global__ void k_scan3(int* __restrict__ deg, const int* __restrict__ bsum,
                        int* __restrict__ ptr, float* __restrict__ dinv, int n) {
    __shared__ int lds[SC_T];
    int tid = threadIdx.x;
    int base = blockIdx.x * SC_B + tid * SC_E;
    int v[SC_E]; int s = 0;
#pragma unroll
    for (int j = 0; j < SC_E; j++) { int i = base + j; v[j] = (i < n) ? deg[i] : 0; s += v[j]; }
    lds[tid] = s; __syncthreads();
    for (int off = 1; off < SC_T; off <<= 1) {
        int t = (tid >= off) ? lds[tid - off] : 0;
        __syncthreads();
        lds[tid] += t;
        __syncthreads();
    }
    int run = bsum[blockIdx.x] + lds[tid] - s;
#pragma unroll
    for (int j = 0; j < SC_E; j++) {
        int i = base + j;
        if (i < n) {
            ptr[i] = run;
            deg[i] = run;                          // becomes fill cursor
            dinv[i] = rsqrtf((float)(v[j] + 1));   // +1 self loop
            run += v[j];
        }
    }
}

__global__ void k_fill(const int* __restrict__ edges, int* __restrict__ cursor,
                       int* __restrict__ adj, int E, int nu) {
    int e = blockIdx.x * blockDim.x + threadIdx.x;
    if (e < E) {
        int u = edges[e];
        int w = nu + edges[E + e];
        int p1 = atomicAdd(&cursor[w], 1); adj[p1] = u;
        int p2 = atomicAdd(&cursor[u], 1); adj[p2] = w;
    }
}

// g0 = dinv .* x, f32x4 per thread
__global__ void k_init(const float* __restrict__ uw, const float* __restrict__ iw,
                       const float* __restrict__ dinv, float* __restrict__ g,
                       int nQuads, int nuQ) {
    int i = blockIdx.x * blockDim.x + threadIdx.x;
    if (i < nQuads) {
        f32x4 x = (i < nuQ) ? ((const f32x4*)uw)[i] : ((const f32x4*)iw)[i - nuQ];
        float s = dinv[i >> 4];
        ((f32x4*)g)[i] = s * x;
    }
}

// quarter-wave (16 lanes) per node; lane j covers dims [4j,4j+3] as f32x4.
//   res = h_{l+1}[c] = dc * (g[c] + sum_{r in N(c)} g[r])
// MODE 1: gn = dc*res (nt), out = x + res (nt)     [x = g[c]*sqrt(deg+1)]
// MODE 2: gn = dc*res (nt), out += res (nt rmw)
// MODE 3: fused epilogue (nt rmw), no gn write
template <int MODE>
__global__ void k_gather4(const int* __restrict__ ptr, const int* __restrict__ adj,
                          const float* __restrict__ dinv, const float* __restrict__ g,
                          float* __restrict__ gn, float* __restrict__ out,
                          const float* __restrict__ uw, const float* __restrict__ aw,
                          int n, int twoE, int nu) {
    int t = blockIdx.x * blockDim.x + threadIdx.x;
    int lane = threadIdx.x & 63;
    int j = lane & 15;                 // dim quad
    int c = (t >> 6) * 4 + (lane >> 4);
    bool valid = (c < n);
    int cc = valid ? c : (n - 1);
    float dc = dinv[cc];
    int s = ptr[cc];
    int e = (cc == n - 1) ? twoE : ptr[cc + 1];
    int deg = e - s;

    f32x4 gc = ((const f32x4*)(g + (size_t)cc * DD))[j];
    f32x4 acc = gc;

    int grpbase = lane & 48;
    for (int base = 0; base < deg; base += 16) {
        int cnt = deg - base; if (cnt > 16) cnt = 16;
        int myr = (j < cnt) ? adj[s + base + j] : 0;
        int k = 0;
        for (; k + 4 <= cnt; k += 4) {
            int r0 = __shfl(myr, grpbase + k, 64);
            int r1 = __shfl(myr, grpbase + k + 1, 64);
            int r2 = __shfl(myr, grpbase + k + 2, 64);
            int r3 = __shfl(myr, grpbase + k + 3, 64);
            f32x4 v0 = ((const f32x4*)(g + (size_t)r0 * DD))[j];
            f32x4 v1 = ((const f32x4*)(g + (size_t)r1 * DD))[j];
            f32x4 v2 = ((const f32x4*)(g + (size_t)r2 * DD))[j];
            f32x4 v3 = ((const f32x4*)(g + (size_t)r3 * DD))[j];
            acc += v0; acc += v1; acc += v2; acc += v3;
        }
        for (; k < cnt; k++) {
            int r = __shfl(myr, grpbase + k, 64);
            acc += ((const f32x4*)(g + (size_t)r * DD))[j];
        }
    }

    if (!valid) return;
    f32x4 res = dc * acc;
    f32x4* gnp  = (f32x4*)(gn  + (size_t)cc * DD) + j;
    f32x4* outp = (f32x4*)(out + (size_t)cc * DD) + j;

    if (MODE == 1) {
        __builtin_nontemporal_store(dc * res, gnp);
        float sq = sqrtf((float)(deg + 1));   // 1/dc
        __builtin_nontemporal_store(gc * sq + res, outp);
    } else if (MODE == 2) {
        __builtin_nontemporal_store(dc * res, gnp);
        f32x4 o = __builtin_nontemporal_load(outp);
        __builtin_nontemporal_store(o + res, outp);
    } else {
        f32x4 o = __builtin_nontemporal_load(outp);
        o = (o + res) * 0.25f;
        if (c < nu) {
            float a0 = aw[0], a1 = aw[1];
            float m = fmaxf(a0, a1);
            float e0 = expf(a0 - m), e1 = expf(a1 - m);
            float al0 = e0 / (e0 + e1);
            float al1 = 1.0f - al0;
            f32x4 u = __builtin_nontemporal_load((const f32x4*)(uw + (size_t)c * DD) + j);
            o = al0 * o + al1 * u;
        }
        __builtin_nontemporal_store(o, outp);
    }
}

extern "C" void kernel_launch(void* const* d_in, const int* in_sizes, int n_in,
                              void* d_out, int out_size, void* d_ws, size_t ws_size,
                              hipStream_t stream) {
    const int* edges = (const int*)d_in[0];   // (2,E)
    const float* uw = (const float*)d_in[1];  // (nu,64)
    const float* iw = (const float*)d_in[2];  // (ni,64)
    const float* aw = (const float*)d_in[3];  // (2,)
    float* out = (float*)d_out;

    const int E = in_sizes[0] / 2;
    const int nu = in_sizes[1] / DD;
    const int ni = in_sizes[2] / DD;
    const int n = nu + ni;
    const int nElem = n * DD;
    const int twoE = 2 * E;

    char* ws = (char*)d_ws;
    size_t off = 0;
    auto alloc = [&](size_t bytes) { size_t r = off; off = (off + bytes + 255) & ~(size_t)255; return r; };
    int* deg   = (int*)(ws + alloc((size_t)n * 4));        // -> cursor after scan3
    int* bsum  = (int*)(ws + alloc((size_t)cdiv(n, SC_B) * 4));
    int* ptr   = (int*)(ws + alloc((size_t)n * 4));
    float* dinv= (float*)(ws + alloc((size_t)n * 4));
    int* adj   = (int*)(ws + alloc((size_t)twoE * 4));
    float* gA  = (float*)(ws + alloc((size_t)nElem * 4));
    float* gB  = (float*)(ws + alloc((size_t)nElem * 4));

    const int B = 256;
    const int gN  = cdiv(n, B);
    const int gE  = cdiv(E, B);
    const int nb  = cdiv(n, SC_B);
    const int nQuads = nElem / 4;
    const int nuQ = nu * DD / 4;
    const int gI  = cdiv(nQuads, B);
    const int gW4 = cdiv((long long)cdiv(n, 4) * 64, B);

    // CSR build
    k_zero<<<gN, B, 0, stream>>>(deg, n);
    k_deg_count<<<gE, B, 0, stream>>>(edges, deg, E, nu);
    k_scan1<<<nb, SC_T, 0, stream>>>(deg, bsum, n);
    k_scan2<<<1, 1024, 0, stream>>>(bsum, nb);
    k_scan3<<<nb, SC_T, 0, stream>>>(deg, bsum, ptr, dinv, n);
    k_fill<<<gE, B, 0, stream>>>(edges, deg /*cursor*/, adj, E, nu);

    // g0 = dinv .* x
    k_init<<<gI, B, 0, stream>>>(uw, iw, dinv, gA, nQuads, nuQ);

    // layer 1: gA->gB, out = x + h1
    k_gather4<1><<<gW4, B, 0, stream>>>(ptr, adj, dinv, gA, gB, out, uw, aw, n, twoE, nu);
    // layer 2: gB->gA, out += h2
    k_gather4<2><<<gW4, B, 0, stream>>>(ptr, adj, dinv, gB, gA, out, uw, aw, n, twoE, nu);
    // layer 3: gA->(reg), fused epilogue
    k_gather4<3><<<gW4, B, 0, stream>>>(ptr, adj, dinv, gA, gB, out, uw, aw, n, twoE, nu);
}

// Round 6
// 1242.892 us; speedup vs baseline: 2.5688x; 1.0102x over previous
//
#include <hip/hip_runtime.h>

#define DD 64
#define SC_T 256
#define SC_E 4
#define SC_B 1024   // elements scanned per block
#define BSHIFT 14   // 16384 nodes per bucket
#define BPB 6       // blocks per bucket in k_bbuild

typedef float f32x4 __attribute__((ext_vector_type(4)));

static inline int cdiv(long long a, int b) { return (int)((a + b - 1) / b); }

__global__ void k_zero(int* __restrict__ p, int n) {
    int i = blockIdx.x * blockDim.x + threadIdx.x;
    if (i < n) p[i] = 0;
}

__global__ void k_deg_count(const int* __restrict__ edges, int* __restrict__ deg,
                            int E, int nu) {
    int e = blockIdx.x * blockDim.x + threadIdx.x;
    if (e < E) {
        atomicAdd(&deg[edges[e]], 1);
        atomicAdd(&deg[nu + edges[E + e]], 1);
    }
}

__global__ void k_scan1(const int* __restrict__ deg, int* __restrict__ bsum, int n) {
    __shared__ int lds[SC_T];
    int tid = threadIdx.x;
    int base = blockIdx.x * SC_B + tid * SC_E;
    int s = 0;
#pragma unroll
    for (int j = 0; j < SC_E; j++) { int i = base + j; if (i < n) s += deg[i]; }
    lds[tid] = s; __syncthreads();
    for (int off = SC_T / 2; off > 0; off >>= 1) {
        if (tid < off) lds[tid] += lds[tid + off];
        __syncthreads();
    }
    if (tid == 0) bsum[blockIdx.x] = lds[0];
}

__global__ void k_scan2(int* __restrict__ bsum, int nb) {
    __shared__ int lds[1024];
    int tid = threadIdx.x;
    int v = (tid < nb) ? bsum[tid] : 0;
    lds[tid] = v; __syncthreads();
    for (int off = 1; off < 1024; off <<= 1) {
        int t = (tid >= off) ? lds[tid - off] : 0;
        __syncthreads();
        lds[tid] += t;
        __syncthreads();
    }
    if (tid < nb) bsum[tid] = lds[tid] - v;   // exclusive
}

__global__ void k_scan3(int* __restrict__ deg, const int* __restrict__ bsum,
                        int* __restrict__ ptr, float* __restrict__ dinv, int n) {
    __shared__ int lds[SC_T];
    int tid = threadIdx.x;
    int base = blockIdx.x * SC_B + tid * SC_E;
    int v[SC_E]; int s = 0;
#pragma unroll
    for (int j = 0; j < SC_E; j++) { int i = base + j; v[j] = (i < n) ? deg[i] : 0; s += v[j]; }
    lds[tid] = s; __syncthreads();
    for (int off = 1; off < SC_T; off <<= 1) {
        int t = (tid >= off) ? lds[tid - off] : 0;
        __syncthreads();
        lds[tid] += t;
        __syncthreads();
    }
    int run = bsum[blockIdx.x] + lds[tid] - s;
#pragma unroll
    for (int j = 0; j < SC_E; j++) {
        int i = base + j;
        if (i < n) {
            ptr[i] = run;
            deg[i] = run;                          // becomes fill cursor
            dinv[i] = rsqrtf((float)(v[j] + 1));   // +1 self loop
            run += v[j];
        }
    }
}

// ---- binned adjacency fill ----

// per-bucket record counts (bucket = target node >> BSHIFT)
__global__ void k_bhist(const int* __restrict__ edges, int E, int nu,
                        int* __restrict__ bcnt) {
    __shared__ int h[64];
    int tid = threadIdx.x;
    if (tid < 64) h[tid] = 0;
    __syncthreads();
    int stride = gridDim.x * blockDim.x;
    for (int e = blockIdx.x * blockDim.x + tid; e < E; e += stride) {
        atomicAdd(&h[edges[e] >> BSHIFT], 1);
        atomicAdd(&h[(nu + edges[E + e]) >> BSHIFT], 1);
    }
    __syncthreads();
    if (tid < 64) { int c = h[tid]; if (c) atomicAdd(&bcnt[tid], c); }
}

// tiny exclusive scan over NB buckets
__global__ void k_bscan(const int* __restrict__ bcnt, int* __restrict__ bbase,
                        int* __restrict__ bcur, int NB) {
    if (threadIdx.x == 0) {
        int run = 0;
        for (int i = 0; i < NB; i++) { bbase[i] = run; bcur[i] = run; run += bcnt[i]; }
        bbase[NB] = run;
    }
}

// scatter (target, neighbor) records into bucket-contiguous staging
__global__ void k_bscatter(const int* __restrict__ edges, int E, int nu,
                           int* __restrict__ bcur, int2* __restrict__ stg,
                           int NB, int CH) {
    __shared__ int h[64];
    __shared__ int base[64];
    int tid = threadIdx.x;
    if (tid < 64) h[tid] = 0;
    __syncthreads();
    int e0 = blockIdx.x * CH;
    int e1 = min(e0 + CH, E);
    for (int e = e0 + tid; e < e1; e += blockDim.x) {
        atomicAdd(&h[edges[e] >> BSHIFT], 1);
        atomicAdd(&h[(nu + edges[E + e]) >> BSHIFT], 1);
    }
    __syncthreads();
    if (tid < NB) {
        int c = h[tid];
        base[tid] = c ? atomicAdd(&bcur[tid], c) : 0;
        h[tid] = 0;
    }
    __syncthreads();
    for (int e = e0 + tid; e < e1; e += blockDim.x) {
        int u = edges[e];
        int w = nu + edges[E + e];
        int b1 = u >> BSHIFT;
        int b2 = w >> BSHIFT;
        int i1 = atomicAdd(&h[b1], 1);
        stg[base[b1] + i1] = make_int2(u, w);
        int i2 = atomicAdd(&h[b2], 1);
        stg[base[b2] + i2] = make_int2(w, u);
    }
}

// per-bucket: place records via L2-local cursor atomics + L2-local adj writes
__global__ void k_bbuild(const int2* __restrict__ stg, const int* __restrict__ bbase,
                         int* __restrict__ cursor, int* __restrict__ adj) {
    int b = blockIdx.x / BPB;
    int sub = blockIdx.x - b * BPB;
    int s = bbase[b], e = bbase[b + 1];
    long long cnt = e - s;
    int i0 = s + (int)(cnt * sub / BPB);
    int i1 = s + (int)(cnt * (sub + 1) / BPB);
    for (int i = i0 + (int)threadIdx.x; i < i1; i += blockDim.x) {
        int2 r = stg[i];
        int pos = atomicAdd(&cursor[r.x], 1);
        adj[pos] = r.y;
    }
}

// ---- feature kernels (unchanged from round 5) ----

__global__ void k_init(const float* __restrict__ uw, const float* __restrict__ iw,
                       const float* __restrict__ dinv, float* __restrict__ g,
                       int nQuads, int nuQ) {
    int i = blockIdx.x * blockDim.x + threadIdx.x;
    if (i < nQuads) {
        f32x4 x = (i < nuQ) ? ((const f32x4*)uw)[i] : ((const f32x4*)iw)[i - nuQ];
        float s = dinv[i >> 4];
        ((f32x4*)g)[i] = s * x;
    }
}

template <int MODE>
__global__ void k_gather4(const int* __restrict__ ptr, const int* __restrict__ adj,
                          const float* __restrict__ dinv, const float* __restrict__ g,
                          float* __restrict__ gn, float* __restrict__ out,
                          const float* __restrict__ uw, const float* __restrict__ aw,
                          int n, int twoE, int nu) {
    int t = blockIdx.x * blockDim.x + threadIdx.x;
    int lane = threadIdx.x & 63;
    int j = lane & 15;                 // dim quad
    int c = (t >> 6) * 4 + (lane >> 4);
    bool valid = (c < n);
    int cc = valid ? c : (n - 1);
    float dc = dinv[cc];
    int s = ptr[cc];
    int e = (cc == n - 1) ? twoE : ptr[cc + 1];
    int deg = e - s;

    f32x4 gc = ((const f32x4*)(g + (size_t)cc * DD))[j];
    f32x4 acc = gc;

    int grpbase = lane & 48;
    for (int base = 0; base < deg; base += 16) {
        int cnt = deg - base; if (cnt > 16) cnt = 16;
        int myr = (j < cnt) ? adj[s + base + j] : 0;
        int k = 0;
        for (; k + 4 <= cnt; k += 4) {
            int r0 = __shfl(myr, grpbase + k, 64);
            int r1 = __shfl(myr, grpbase + k + 1, 64);
            int r2 = __shfl(myr, grpbase + k + 2, 64);
            int r3 = __shfl(myr, grpbase + k + 3, 64);
            f32x4 v0 = ((const f32x4*)(g + (size_t)r0 * DD))[j];
            f32x4 v1 = ((const f32x4*)(g + (size_t)r1 * DD))[j];
            f32x4 v2 = ((const f32x4*)(g + (size_t)r2 * DD))[j];
            f32x4 v3 = ((const f32x4*)(g + (size_t)r3 * DD))[j];
            acc += v0; acc += v1; acc += v2; acc += v3;
        }
        for (; k < cnt; k++) {
            int r = __shfl(myr, grpbase + k, 64);
            acc += ((const f32x4*)(g + (size_t)r * DD))[j];
        }
    }

    if (!valid) return;
    f32x4 res = dc * acc;
    f32x4* gnp  = (f32x4*)(gn  + (size_t)cc * DD) + j;
    f32x4* outp = (f32x4*)(out + (size_t)cc * DD) + j;

    if (MODE == 1) {
        __builtin_nontemporal_store(dc * res, gnp);
        float sq = sqrtf((float)(deg + 1));   // 1/dc
        __builtin_nontemporal_store(gc * sq + res, outp);
    } else if (MODE == 2) {
        __builtin_nontemporal_store(dc * res, gnp);
        f32x4 o = __builtin_nontemporal_load(outp);
        __builtin_nontemporal_store(o + res, outp);
    } else {
        f32x4 o = __builtin_nontemporal_load(outp);
        o = (o + res) * 0.25f;
        if (c < nu) {
            float a0 = aw[0], a1 = aw[1];
            float m = fmaxf(a0, a1);
            float e0 = expf(a0 - m), e1 = expf(a1 - m);
            float al0 = e0 / (e0 + e1);
            float al1 = 1.0f - al0;
            f32x4 u = __builtin_nontemporal_load((const f32x4*)(uw + (size_t)c * DD) + j);
            o = al0 * o + al1 * u;
        }
        __builtin_nontemporal_store(o, outp);
    }
}

extern "C" void kernel_launch(void* const* d_in, const int* in_sizes, int n_in,
                              void* d_out, int out_size, void* d_ws, size_t ws_size,
                              hipStream_t stream) {
    const int* edges = (const int*)d_in[0];   // (2,E)
    const float* uw = (const float*)d_in[1];  // (nu,64)
    const float* iw = (const float*)d_in[2];  // (ni,64)
    const float* aw = (const float*)d_in[3];  // (2,)
    float* out = (float*)d_out;

    const int E = in_sizes[0] / 2;
    const int nu = in_sizes[1] / DD;
    const int ni = in_sizes[2] / DD;
    const int n = nu + ni;
    const int nElem = n * DD;
    const int twoE = 2 * E;
    const int NB = (n + (1 << BSHIFT) - 1) >> BSHIFT;   // <= 64

    char* ws = (char*)d_ws;
    size_t off = 0;
    auto alloc = [&](size_t bytes) { size_t r = off; off = (off + bytes + 255) & ~(size_t)255; return r; };
    int* deg   = (int*)(ws + alloc((size_t)n * 4));        // -> cursor after scan3
    int* bsum  = (int*)(ws + alloc((size_t)cdiv(n, SC_B) * 4));
    int* ptr   = (int*)(ws + alloc((size_t)n * 4));
    float* dinv= (float*)(ws + alloc((size_t)n * 4));
    int* adj   = (int*)(ws + alloc((size_t)twoE * 4));
    int* bcnt  = (int*)(ws + alloc(64 * 4));
    int* bbase = (int*)(ws + alloc(65 * 4));
    int* bcur  = (int*)(ws + alloc(64 * 4));
    float* gA  = (float*)(ws + alloc((size_t)nElem * 4));
    float* gB  = (float*)(ws + alloc((size_t)nElem * 4));
    int2* stg  = (int2*)gB;   // staging records alias gB (only used before gathers)

    const int B = 256;
    const int gN  = cdiv(n, B);
    const int gE  = cdiv(E, B);
    const int nb  = cdiv(n, SC_B);
    const int nQuads = nElem / 4;
    const int nuQ = nu * DD / 4;
    const int gI  = cdiv(nQuads, B);
    const int gW4 = cdiv((long long)cdiv(n, 4) * 64, B);
    const int CH  = 4096;
    const int gSC = cdiv(E, CH);

    // degree + per-bucket record counts
    k_zero<<<gN, B, 0, stream>>>(deg, n);
    k_zero<<<1, 64, 0, stream>>>(bcnt, 64);
    k_deg_count<<<gE, B, 0, stream>>>(edges, deg, E, nu);
    k_bhist<<<512, B, 0, stream>>>(edges, E, nu, bcnt);

    // node-level scan (ptr, dinv, cursor) + bucket-level scan
    k_scan1<<<nb, SC_T, 0, stream>>>(deg, bsum, n);
    k_scan2<<<1, 1024, 0, stream>>>(bsum, nb);
    k_scan3<<<nb, SC_T, 0, stream>>>(deg, bsum, ptr, dinv, n);
    k_bscan<<<1, 64, 0, stream>>>(bcnt, bbase, bcur, NB);

    // binned fill
    k_bscatter<<<gSC, B, 0, stream>>>(edges, E, nu, bcur, stg, NB, CH);
    k_bbuild<<<NB * BPB, B, 0, stream>>>(stg, bbase, deg /*cursor*/, adj);

    // g0 = dinv .* x
    k_init<<<gI, B, 0, stream>>>(uw, iw, dinv, gA, nQuads, nuQ);

    // layer 1: gA->gB, out = x + h1
    k_gather4<1><<<gW4, B, 0, stream>>>(ptr, adj, dinv, gA, gB, out, uw, aw, n, twoE, nu);
    // layer 2: gB->gA, out += h2
    k_gather4<2><<<gW4, B, 0, stream>>>(ptr, adj, dinv, gB, gA, out, uw, aw, n, twoE, nu);
    // layer 3: gA->(reg), fused epilogue
    k_gather4<3><<<gW4, B, 0, stream>>>(ptr, adj, dinv, gA, gB, out, uw, aw, n, twoE, nu);
}

// Round 7
// 898.984 us; speedup vs baseline: 3.5515x; 1.3826x over previous
//
#include <hip/hip_runtime.h>

#define DD 64
#define BSHIFT 12              // 4096 nodes per bucket
#define BNODES (1 << BSHIFT)
#define NBMAX 256

typedef float f32x4 __attribute__((ext_vector_type(4)));

static inline int cdiv(long long a, int b) { return (int)((a + b - 1) / b); }

__global__ void k_zero(int* __restrict__ p, int n) {
    int i = blockIdx.x * blockDim.x + threadIdx.x;
    if (i < n) p[i] = 0;
}

// per-bucket record counts (bucket = target node >> BSHIFT)
__global__ void k_bhist(const int* __restrict__ edges, int E, int nu,
                        int* __restrict__ bcnt) {
    __shared__ int h[NBMAX];
    int tid = threadIdx.x;
    h[tid] = 0;
    __syncthreads();
    int stride = gridDim.x * blockDim.x;
    for (int e = blockIdx.x * blockDim.x + tid; e < E; e += stride) {
        atomicAdd(&h[edges[e] >> BSHIFT], 1);
        atomicAdd(&h[(nu + edges[E + e]) >> BSHIFT], 1);
    }
    __syncthreads();
    int c = h[tid];
    if (c) atomicAdd(&bcnt[tid], c);
}

// tiny exclusive scan over NB buckets
__global__ void k_bscan(const int* __restrict__ bcnt, int* __restrict__ bbase,
                        int* __restrict__ bcur, int NB) {
    if (threadIdx.x == 0) {
        int run = 0;
        for (int i = 0; i < NB; i++) { bbase[i] = run; bcur[i] = run; run += bcnt[i]; }
        bbase[NB] = run;
    }
}

// scatter (target, neighbor) records into bucket-contiguous staging
__global__ void k_bscatter(const int* __restrict__ edges, int E, int nu,
                           int* __restrict__ bcur, int2* __restrict__ stg,
                           int NB, int CH) {
    __shared__ int h[NBMAX];
    __shared__ int base[NBMAX];
    int tid = threadIdx.x;
    h[tid] = 0;
    __syncthreads();
    int e0 = blockIdx.x * CH;
    int e1 = min(e0 + CH, E);
    for (int e = e0 + tid; e < e1; e += blockDim.x) {
        atomicAdd(&h[edges[e] >> BSHIFT], 1);
        atomicAdd(&h[(nu + edges[E + e]) >> BSHIFT], 1);
    }
    __syncthreads();
    {
        int c = h[tid];
        base[tid] = c ? atomicAdd(&bcur[tid], c) : 0;
        h[tid] = 0;
    }
    __syncthreads();
    for (int e = e0 + tid; e < e1; e += blockDim.x) {
        int u = edges[e];
        int w = nu + edges[E + e];
        int b1 = u >> BSHIFT;
        int b2 = w >> BSHIFT;
        int i1 = atomicAdd(&h[b1], 1);
        stg[base[b1] + i1] = make_int2(u, w);
        int i2 = atomicAdd(&h[b2], 1);
        stg[base[b2] + i2] = make_int2(w, u);
    }
}

// one block per bucket: LDS counting sort -> adj; also emits ptr and dinv.
__global__ void k_bsort(const int2* __restrict__ stg, const int* __restrict__ bbase,
                        int* __restrict__ adj, int* __restrict__ ptr,
                        float* __restrict__ dinv, int n) {
    __shared__ int cnt[BNODES];
    __shared__ int tsum[256];
    int b = blockIdx.x;
    int tid = threadIdx.x;
    int node0 = b << BSHIFT;
    int s = bbase[b], e = bbase[b + 1];

    for (int i = tid; i < BNODES; i += 256) cnt[i] = 0;
    __syncthreads();
    for (int i = s + tid; i < e; i += 256) {
        int2 r = stg[i];
        atomicAdd(&cnt[r.x - node0], 1);
    }
    __syncthreads();

    // block exclusive scan over cnt[0..BNODES): 16 per thread
    int base16 = tid * 16;
    int loc = 0;
#pragma unroll
    for (int j = 0; j < 16; j++) loc += cnt[base16 + j];
    tsum[tid] = loc;
    __syncthreads();
    for (int off = 1; off < 256; off <<= 1) {
        int t = (tid >= off) ? tsum[tid - off] : 0;
        __syncthreads();
        tsum[tid] += t;
        __syncthreads();
    }
    int run = (tid > 0) ? tsum[tid - 1] : 0;
#pragma unroll
    for (int j = 0; j < 16; j++) {
        int node = node0 + base16 + j;
        int c = cnt[base16 + j];
        cnt[base16 + j] = run;          // exclusive prefix -> cursor
        if (node < n) {
            ptr[node] = s + run;
            dinv[node] = rsqrtf((float)(c + 1));   // +1 self loop
        }
        run += c;
    }
    __syncthreads();

    // place neighbors: all adj writes land in this bucket's window (one XCD)
    for (int i = s + tid; i < e; i += 256) {
        int2 r = stg[i];
        int pos = atomicAdd(&cnt[r.x - node0], 1);
        adj[s + pos] = r.y;
    }
}

// g0 = dinv .* x, f32x4 per thread
__global__ void k_init(const float* __restrict__ uw, const float* __restrict__ iw,
                       const float* __restrict__ dinv, float* __restrict__ g,
                       int nQuads, int nuQ) {
    int i = blockIdx.x * blockDim.x + threadIdx.x;
    if (i < nQuads) {
        f32x4 x = (i < nuQ) ? ((const f32x4*)uw)[i] : ((const f32x4*)iw)[i - nuQ];
        float s = dinv[i >> 4];
        ((f32x4*)g)[i] = s * x;
    }
}

// quarter-wave (16 lanes) per node; lane j covers dims [4j,4j+3] as f32x4.
template <int MODE>
__global__ void k_gather4(const int* __restrict__ ptr, const int* __restrict__ adj,
                          const float* __restrict__ dinv, const float* __restrict__ g,
                          float* __restrict__ gn, float* __restrict__ out,
                          const float* __restrict__ uw, const float* __restrict__ aw,
                          int n, int twoE, int nu) {
    int t = blockIdx.x * blockDim.x + threadIdx.x;
    int lane = threadIdx.x & 63;
    int j = lane & 15;                 // dim quad
    int c = (t >> 6) * 4 + (lane >> 4);
    bool valid = (c < n);
    int cc = valid ? c : (n - 1);
    float dc = dinv[cc];
    int s = ptr[cc];
    int e = (cc == n - 1) ? twoE : ptr[cc + 1];
    int deg = e - s;

    f32x4 gc = ((const f32x4*)(g + (size_t)cc * DD))[j];
    f32x4 acc = gc;

    int grpbase = lane & 48;
    for (int base = 0; base < deg; base += 16) {
        int cnt = deg - base; if (cnt > 16) cnt = 16;
        int myr = (j < cnt) ? adj[s + base + j] : 0;
        int k = 0;
        for (; k + 4 <= cnt; k += 4) {
            int r0 = __shfl(myr, grpbase + k, 64);
            int r1 = __shfl(myr, grpbase + k + 1, 64);
            int r2 = __shfl(myr, grpbase + k + 2, 64);
            int r3 = __shfl(myr, grpbase + k + 3, 64);
            f32x4 v0 = ((const f32x4*)(g + (size_t)r0 * DD))[j];
            f32x4 v1 = ((const f32x4*)(g + (size_t)r1 * DD))[j];
            f32x4 v2 = ((const f32x4*)(g + (size_t)r2 * DD))[j];
            f32x4 v3 = ((const f32x4*)(g + (size_t)r3 * DD))[j];
            acc += v0; acc += v1; acc += v2; acc += v3;
        }
        for (; k < cnt; k++) {
            int r = __shfl(myr, grpbase + k, 64);
            acc += ((const f32x4*)(g + (size_t)r * DD))[j];
        }
    }

    if (!valid) return;
    f32x4 res = dc * acc;
    f32x4* gnp  = (f32x4*)(gn  + (size_t)cc * DD) + j;
    f32x4* outp = (f32x4*)(out + (size_t)cc * DD) + j;

    if (MODE == 1) {
        __builtin_nontemporal_store(dc * res, gnp);
        float sq = sqrtf((float)(deg + 1));   // 1/dc
        __builtin_nontemporal_store(gc * sq + res, outp);
    } else if (MODE == 2) {
        __builtin_nontemporal_store(dc * res, gnp);
        f32x4 o = __builtin_nontemporal_load(outp);
        __builtin_nontemporal_store(o + res, outp);
    } else {
        f32x4 o = __builtin_nontemporal_load(outp);
        o = (o + res) * 0.25f;
        if (c < nu) {
            float a0 = aw[0], a1 = aw[1];
            float m = fmaxf(a0, a1);
            float e0 = expf(a0 - m), e1 = expf(a1 - m);
            float al0 = e0 / (e0 + e1);
            float al1 = 1.0f - al0;
            f32x4 u = __builtin_nontemporal_load((const f32x4*)(uw + (size_t)c * DD) + j);
            o = al0 * o + al1 * u;
        }
        __builtin_nontemporal_store(o, outp);
    }
}

extern "C" void kernel_launch(void* const* d_in, const int* in_sizes, int n_in,
                              void* d_out, int out_size, void* d_ws, size_t ws_size,
                              hipStream_t stream) {
    const int* edges = (const int*)d_in[0];   // (2,E)
    const float* uw = (const float*)d_in[1];  // (nu,64)
    const float* iw = (const float*)d_in[2];  // (ni,64)
    const float* aw = (const float*)d_in[3];  // (2,)
    float* out = (float*)d_out;

    const int E = in_sizes[0] / 2;
    const int nu = in_sizes[1] / DD;
    const int ni = in_sizes[2] / DD;
    const int n = nu + ni;
    const int nElem = n * DD;
    const int twoE = 2 * E;
    const int NB = (n + BNODES - 1) >> BSHIFT;   // 171 for n=700k

    char* ws = (char*)d_ws;
    size_t off = 0;
    auto alloc = [&](size_t bytes) { size_t r = off; off = (off + bytes + 255) & ~(size_t)255; return r; };
    int* ptr   = (int*)(ws + alloc((size_t)n * 4));
    float* dinv= (float*)(ws + alloc((size_t)n * 4));
    int* adj   = (int*)(ws + alloc((size_t)twoE * 4));
    int* bcnt  = (int*)(ws + alloc(NBMAX * 4));
    int* bbase = (int*)(ws + alloc((NBMAX + 1) * 4));
    int* bcur  = (int*)(ws + alloc(NBMAX * 4));
    float* gA  = (float*)(ws + alloc((size_t)nElem * 4));
    float* gB  = (float*)(ws + alloc((size_t)nElem * 4));
    int2* stg  = (int2*)gB;   // staging records alias gB (dead before gather 1 writes it)

    const int B = 256;
    const int nQuads = nElem / 4;
    const int nuQ = nu * DD / 4;
    const int gI  = cdiv(nQuads, B);
    const int gW4 = cdiv((long long)cdiv(n, 4) * 64, B);
    const int CH  = 4096;
    const int gSC = cdiv(E, CH);

    // bucketed CSR build (no node-level atomics on global, no global scans)
    k_zero<<<1, NBMAX, 0, stream>>>(bcnt, NBMAX);
    k_bhist<<<512, NBMAX, 0, stream>>>(edges, E, nu, bcnt);
    k_bscan<<<1, 64, 0, stream>>>(bcnt, bbase, bcur, NB);
    k_bscatter<<<gSC, NBMAX, 0, stream>>>(edges, E, nu, bcur, stg, NB, CH);
    k_bsort<<<NB, 256, 0, stream>>>(stg, bbase, adj, ptr, dinv, n);

    // g0 = dinv .* x
    k_init<<<gI, B, 0, stream>>>(uw, iw, dinv, gA, nQuads, nuQ);

    // layer 1: gA->gB, out = x + h1
    k_gather4<1><<<gW4, B, 0, stream>>>(ptr, adj, dinv, gA, gB, out, uw, aw, n, twoE, nu);
    // layer 2: gB->gA, out += h2
    k_gather4<2><<<gW4, B, 0, stream>>>(ptr, adj, dinv, gB, gA, out, uw, aw, n, twoE, nu);
    // layer 3: gA->(reg), fused epilogue
    k_gather4<3><<<gW4, B, 0, stream>>>(ptr, adj, dinv, gA, gB, out, uw, aw, n, twoE, nu);
}

// Round 9
// 590.698 us; speedup vs baseline: 5.4051x; 1.5219x over previous
//
#include <hip/hip_runtime.h>

#define DD 64
#define BSHIFT 12              // 4096 nodes per bucket
#define BNODES (1 << BSHIFT)
#define NBMAX 256

typedef float f32x4 __attribute__((ext_vector_type(4)));
typedef unsigned int u32x2 __attribute__((ext_vector_type(2)));
typedef unsigned int u32;
typedef unsigned short u16;

static inline int cdiv(long long a, int b) { return (int)((a + b - 1) / b); }

// ---- bf16 helpers (RNE) ----
__device__ inline f32x4 bf4_to_f(u32x2 v) {
    f32x4 r;
    r.x = __uint_as_float(v.x << 16);
    r.y = __uint_as_float(v.x & 0xFFFF0000u);
    r.z = __uint_as_float(v.y << 16);
    r.w = __uint_as_float(v.y & 0xFFFF0000u);
    return r;
}
__device__ inline u32 pack_bf2(float a, float b) {
    u32 ua = __float_as_uint(a);
    u32 ub = __float_as_uint(b);
    u32 lo = (ua + 0x7FFFu + ((ua >> 16) & 1u)) >> 16;
    u32 hi = (ub + 0x7FFFu + ((ub >> 16) & 1u)) >> 16;
    return lo | (hi << 16);
}
__device__ inline u32x2 pack_bf4(f32x4 v) {
    u32x2 r;
    r.x = pack_bf2(v.x, v.y);
    r.y = pack_bf2(v.z, v.w);
    return r;
}

__global__ void k_zero(int* __restrict__ p, int n) {
    int i = blockIdx.x * blockDim.x + threadIdx.x;
    if (i < n) p[i] = 0;
}

// per-bucket record counts (bucket = target node >> BSHIFT)
__global__ void k_bhist(const int* __restrict__ edges, int E, int nu,
                        int* __restrict__ bcnt) {
    __shared__ int h[NBMAX];
    int tid = threadIdx.x;
    h[tid] = 0;
    __syncthreads();
    int stride = gridDim.x * blockDim.x;
    for (int e = blockIdx.x * blockDim.x + tid; e < E; e += stride) {
        atomicAdd(&h[edges[e] >> BSHIFT], 1);
        atomicAdd(&h[(nu + edges[E + e]) >> BSHIFT], 1);
    }
    __syncthreads();
    int c = h[tid];
    if (c) atomicAdd(&bcnt[tid], c);
}

// tiny exclusive scan over NB buckets
__global__ void k_bscan(const int* __restrict__ bcnt, int* __restrict__ bbase,
                        int* __restrict__ bcur, int NB) {
    if (threadIdx.x == 0) {
        int run = 0;
        for (int i = 0; i < NB; i++) { bbase[i] = run; bcur[i] = run; run += bcnt[i]; }
        bbase[NB] = run;
    }
}

// scatter (target, neighbor) records into bucket-contiguous staging
__global__ void k_bscatter(const int* __restrict__ edges, int E, int nu,
                           int* __restrict__ bcur, int2* __restrict__ stg,
                           int NB, int CH) {
    __shared__ int h[NBMAX];
    __shared__ int base[NBMAX];
    int tid = threadIdx.x;
    h[tid] = 0;
    __syncthreads();
    int e0 = blockIdx.x * CH;
    int e1 = min(e0 + CH, E);
    for (int e = e0 + tid; e < e1; e += blockDim.x) {
        atomicAdd(&h[edges[e] >> BSHIFT], 1);
        atomicAdd(&h[(nu + edges[E + e]) >> BSHIFT], 1);
    }
    __syncthreads();
    {
        int c = h[tid];
        base[tid] = c ? atomicAdd(&bcur[tid], c) : 0;
        h[tid] = 0;
    }
    __syncthreads();
    for (int e = e0 + tid; e < e1; e += blockDim.x) {
        int u = edges[e];
        int w = nu + edges[E + e];
        int b1 = u >> BSHIFT;
        int b2 = w >> BSHIFT;
        int i1 = atomicAdd(&h[b1], 1);
        stg[base[b1] + i1] = make_int2(u, w);
        int i2 = atomicAdd(&h[b2], 1);
        stg[base[b2] + i2] = make_int2(w, u);
    }
}

// one block per bucket: LDS counting sort -> adj; also emits ptr and dinv.
__global__ void k_bsort(const int2* __restrict__ stg, const int* __restrict__ bbase,
                        int* __restrict__ adj, int* __restrict__ ptr,
                        float* __restrict__ dinv, int n) {
    __shared__ int cnt[BNODES];
    __shared__ int tsum[256];
    int b = blockIdx.x;
    int tid = threadIdx.x;
    int node0 = b << BSHIFT;
    int s = bbase[b], e = bbase[b + 1];

    for (int i = tid; i < BNODES; i += 256) cnt[i] = 0;
    __syncthreads();
    for (int i = s + tid; i < e; i += 256) {
        int2 r = stg[i];
        atomicAdd(&cnt[r.x - node0], 1);
    }
    __syncthreads();

    int base16 = tid * 16;
    int loc = 0;
#pragma unroll
    for (int j = 0; j < 16; j++) loc += cnt[base16 + j];
    tsum[tid] = loc;
    __syncthreads();
    for (int off = 1; off < 256; off <<= 1) {
        int t = (tid >= off) ? tsum[tid - off] : 0;
        __syncthreads();
        tsum[tid] += t;
        __syncthreads();
    }
    int run = (tid > 0) ? tsum[tid - 1] : 0;
#pragma unroll
    for (int j = 0; j < 16; j++) {
        int node = node0 + base16 + j;
        int c = cnt[base16 + j];
        cnt[base16 + j] = run;
        if (node < n) {
            ptr[node] = s + run;
            dinv[node] = rsqrtf((float)(c + 1));   // +1 self loop
        }
        run += c;
    }
    __syncthreads();

    for (int i = s + tid; i < e; i += 256) {
        int2 r = stg[i];
        int pos = atomicAdd(&cnt[r.x - node0], 1);
        adj[s + pos] = r.y;
    }
}

// g0 = dinv .* x  (bf16 packed)
__global__ void k_init(const float* __restrict__ uw, const float* __restrict__ iw,
                       const float* __restrict__ dinv, u16* __restrict__ g,
                       int nQuads, int nuQ) {
    int i = blockIdx.x * blockDim.x + threadIdx.x;
    if (i < nQuads) {
        f32x4 x = (i < nuQ) ? ((const f32x4*)uw)[i] : ((const f32x4*)iw)[i - nuQ];
        float s = dinv[i >> 4];
        __builtin_nontemporal_store(pack_bf4(s * x), (u32x2*)g + i);
    }
}

// quarter-wave (16 lanes) per node, bf16 rows (u32x2 = 4 bf16 per lane).
// gn = dinv[c]^2 * (g[c] + sum_{r in N(c)} g[r])      (layers 1 and 2)
__global__ void k_gatherb(const int* __restrict__ ptr, const int* __restrict__ adj,
                          const float* __restrict__ dinv, const u16* __restrict__ g,
                          u16* __restrict__ gn, int n, int twoE) {
    int t = blockIdx.x * blockDim.x + threadIdx.x;
    int lane = threadIdx.x & 63;
    int j = lane & 15;
    int c = (t >> 6) * 4 + (lane >> 4);
    bool valid = (c < n);
    int cc = valid ? c : (n - 1);
    float dc = dinv[cc];
    int s = ptr[cc];
    int e = (cc == n - 1) ? twoE : ptr[cc + 1];
    int deg = e - s;

    f32x4 acc = bf4_to_f(((const u32x2*)(g + (size_t)cc * DD))[j]);

    int grpbase = lane & 48;
    for (int base = 0; base < deg; base += 16) {
        int cnt = deg - base; if (cnt > 16) cnt = 16;
        int myr = (j < cnt) ? adj[s + base + j] : 0;
        int k = 0;
        for (; k + 4 <= cnt; k += 4) {
            int r0 = __shfl(myr, grpbase + k, 64);
            int r1 = __shfl(myr, grpbase + k + 1, 64);
            int r2 = __shfl(myr, grpbase + k + 2, 64);
            int r3 = __shfl(myr, grpbase + k + 3, 64);
            u32x2 v0 = ((const u32x2*)(g + (size_t)r0 * DD))[j];
            u32x2 v1 = ((const u32x2*)(g + (size_t)r1 * DD))[j];
            u32x2 v2 = ((const u32x2*)(g + (size_t)r2 * DD))[j];
            u32x2 v3 = ((const u32x2*)(g + (size_t)r3 * DD))[j];
            acc += bf4_to_f(v0); acc += bf4_to_f(v1);
            acc += bf4_to_f(v2); acc += bf4_to_f(v3);
        }
        for (; k < cnt; k++) {
            int r = __shfl(myr, grpbase + k, 64);
            acc += bf4_to_f(((const u32x2*)(g + (size_t)r * DD))[j]);
        }
    }

    if (!valid) return;
    f32x4 gnv = (dc * dc) * acc;     // dinv * h_next
    __builtin_nontemporal_store(pack_bf4(gnv), (u32x2*)(gn + (size_t)cc * DD) + j);
}

// epilogue: h3 in-register; acc = x + h1 + h2 + h3; interest = acc/4; user mix.
// h1 = g1[c]*sq, h2 = g2[c]*sq, sq = sqrt(deg+1) = 1/dc; x from uw/iw.
__global__ void k_gfinal(const int* __restrict__ ptr, const int* __restrict__ adj,
                         const float* __restrict__ dinv, const u16* __restrict__ g2,
                         const u16* __restrict__ g1,
                         const float* __restrict__ uw, const float* __restrict__ iw,
                         const float* __restrict__ aw, float* __restrict__ out,
                         int n, int twoE, int nu) {
    int t = blockIdx.x * blockDim.x + threadIdx.x;
    int lane = threadIdx.x & 63;
    int j = lane & 15;
    int c = (t >> 6) * 4 + (lane >> 4);
    bool valid = (c < n);
    int cc = valid ? c : (n - 1);
    float dc = dinv[cc];
    int s = ptr[cc];
    int e = (cc == n - 1) ? twoE : ptr[cc + 1];
    int deg = e - s;

    f32x4 g2c = bf4_to_f(((const u32x2*)(g2 + (size_t)cc * DD))[j]);
    f32x4 acc = g2c;

    int grpbase = lane & 48;
    for (int base = 0; base < deg; base += 16) {
        int cnt = deg - base; if (cnt > 16) cnt = 16;
        int myr = (j < cnt) ? adj[s + base + j] : 0;
        int k = 0;
        for (; k + 4 <= cnt; k += 4) {
            int r0 = __shfl(myr, grpbase + k, 64);
            int r1 = __shfl(myr, grpbase + k + 1, 64);
            int r2 = __shfl(myr, grpbase + k + 2, 64);
            int r3 = __shfl(myr, grpbase + k + 3, 64);
            u32x2 v0 = ((const u32x2*)(g2 + (size_t)r0 * DD))[j];
            u32x2 v1 = ((const u32x2*)(g2 + (size_t)r1 * DD))[j];
            u32x2 v2 = ((const u32x2*)(g2 + (size_t)r2 * DD))[j];
            u32x2 v3 = ((const u32x2*)(g2 + (size_t)r3 * DD))[j];
            acc += bf4_to_f(v0); acc += bf4_to_f(v1);
            acc += bf4_to_f(v2); acc += bf4_to_f(v3);
        }
        for (; k < cnt; k++) {
            int r = __shfl(myr, grpbase + k, 64);
            acc += bf4_to_f(((const u32x2*)(g2 + (size_t)r * DD))[j]);
        }
    }

    if (!valid) return;
    f32x4 h3 = dc * acc;
    float sq = sqrtf((float)(deg + 1));   // 1/dc
    f32x4 h2 = g2c * sq;
    f32x4 h1 = bf4_to_f(((const u32x2*)(g1 + (size_t)cc * DD))[j]) * sq;
    f32x4 x = (c < nu) ? __builtin_nontemporal_load((const f32x4*)(uw + (size_t)c * DD) + j)
                       : __builtin_nontemporal_load((const f32x4*)(iw + (size_t)(c - nu) * DD) + j);
    f32x4 interest = (x + h1 + h2 + h3) * 0.25f;
    f32x4 o;
    if (c < nu) {
        float a0 = aw[0], a1 = aw[1];
        float m = fmaxf(a0, a1);
        float e0 = expf(a0 - m), e1 = expf(a1 - m);
        float al0 = e0 / (e0 + e1);
        o = al0 * interest + (1.0f - al0) * x;
    } else {
        o = interest;
    }
    __builtin_nontemporal_store(o, (f32x4*)(out + (size_t)cc * DD) + j);
}

extern "C" void kernel_launch(void* const* d_in, const int* in_sizes, int n_in,
                              void* d_out, int out_size, void* d_ws, size_t ws_size,
                              hipStream_t stream) {
    const int* edges = (const int*)d_in[0];   // (2,E)
    const float* uw = (const float*)d_in[1];  // (nu,64)
    const float* iw = (const float*)d_in[2];  // (ni,64)
    const float* aw = (const float*)d_in[3];  // (2,)
    float* out = (float*)d_out;

    const int E = in_sizes[0] / 2;
    const int nu = in_sizes[1] / DD;
    const int ni = in_sizes[2] / DD;
    const int n = nu + ni;
    const int nElem = n * DD;
    const int twoE = 2 * E;
    const int NB = (n + BNODES - 1) >> BSHIFT;

    char* ws = (char*)d_ws;
    size_t off = 0;
    auto alloc = [&](size_t bytes) { size_t r = off; off = (off + bytes + 255) & ~(size_t)255; return r; };
    int* ptr   = (int*)(ws + alloc((size_t)n * 4));
    float* dinv= (float*)(ws + alloc((size_t)n * 4));
    int* adj   = (int*)(ws + alloc((size_t)twoE * 4));
    int* bcnt  = (int*)(ws + alloc(NBMAX * 4));
    int* bbase = (int*)(ws + alloc((NBMAX + 1) * 4));
    int* bcur  = (int*)(ws + alloc(NBMAX * 4));
    u16* g0    = (u16*)(ws + alloc((size_t)nElem * 2));
    u16* g1    = (u16*)(ws + alloc((size_t)nElem * 2));
    // g2 slot also hosts staging records (stg dead before layer-2 writes g2)
    size_t g2bytes = (size_t)nElem * 2;
    size_t stbytes = (size_t)twoE * 8;
    u16* g2    = (u16*)(ws + alloc(g2bytes > stbytes ? g2bytes : stbytes));
    int2* stg  = (int2*)g2;

    const int B = 256;
    const int nQuads = nElem / 4;
    const int nuQ = nu * DD / 4;
    const int gI  = cdiv(nQuads, B);
    const int gW4 = cdiv((long long)cdiv(n, 4) * 64, B);
    const int CH  = 4096;
    const int gSC = cdiv(E, CH);

    // bucketed CSR build
    k_zero<<<1, NBMAX, 0, stream>>>(bcnt, NBMAX);
    k_bhist<<<512, NBMAX, 0, stream>>>(edges, E, nu, bcnt);
    k_bscan<<<1, 64, 0, stream>>>(bcnt, bbase, bcur, NB);
    k_bscatter<<<gSC, NBMAX, 0, stream>>>(edges, E, nu, bcur, stg, NB, CH);
    k_bsort<<<NB, 256, 0, stream>>>(stg, bbase, adj, ptr, dinv, n);

    // g0 = dinv .* x (bf16)
    k_init<<<gI, B, 0, stream>>>(uw, iw, dinv, g0, nQuads, nuQ);

    // layer 1: g0 -> g1
    k_gatherb<<<gW4, B, 0, stream>>>(ptr, adj, dinv, g0, g1, n, twoE);
    // layer 2: g1 -> g2
    k_gatherb<<<gW4, B, 0, stream>>>(ptr, adj, dinv, g1, g2, n, twoE);
    // layer 3 + fused acc/epilogue: g2 -> out
    k_gfinal<<<gW4, B, 0, stream>>>(ptr, adj, dinv, g2, g1, uw, iw, aw, out, n, twoE, nu);
}